// Round 5
// baseline (84.702 us; speedup 1.0000x reference)
//
#include <hip/hip_runtime.h>

// Chamfer loss: B=32, N=M=2048, D=3, fp32 in, scalar fp32 out.
// loss = sum_b [ sum_m min_n d2 + sum_n min_m d2 ] / B
//
// v4 (resubmit; round-4 bench was a broker timeout, no data):
// LDS-bus fix. Broadcast ds_read_b128 is byte-paced (~12 cyc/wave-read,
// LDS pipe shared per-CU by 4 SIMDs). At QPT=4 the scan was LDS-bound 1.5x.
// QPT=8: one b128 read feeds 64 VALU insts -> LDS demand 75% of capacity,
// VALU binding again (floor ~14 us at 4 inst/pair: 3 fma + 1 min3-half).
//  - Dot form: stage (px,py,pz,h=0.5*|p|^2); s = h - q.p (3 fma, free neg
//    modifiers); d2 = max(0, 2*s_min + |q|^2) once per query (min monotone).
//  - SSPLIT=16 shards x 2 dirs x 32 batches = 1024 blocks = 4/CU = 16
//    waves/CU co-resident. 2KB LDS/block.
//  - Shard partials stored (no atomics) to 8MB ws; reduce kernel does
//    min-over-16-shards then sum. atomicMin / direct-sum fallbacks.

constexpr int B_SZ    = 32;
constexpr int NPTS    = 2048;
constexpr int BLOCK   = 256;
constexpr int QPT     = 8;                  // queries per thread (= whole cloud)
constexpr int SSPLIT  = 16;                 // staged-cloud shards
constexpr int NQ      = 2 * B_SZ * NPTS;    // 131072 query slots (both dirs)

template <int SSP, int MODE>  // MODE 0=store partials, 1=atomicMin, 2=direct sum
__global__ __launch_bounds__(BLOCK, 4)
void chamfer_min_kernel(const float* __restrict__ x, const float* __restrict__ y,
                        float* __restrict__ ws, float* __restrict__ out) {
    constexpr int SPTS = NPTS / SSP;
    __shared__ float4 pts[SPTS];
    __shared__ float  wsum[BLOCK / 64];

    const int id  = blockIdx.x;
    const int sh  = id % SSP;
    int t         = id / SSP;
    const int b   = t % B_SZ;
    const int dir = t / B_SZ;

    const float* qb = (dir == 0) ? x : y;
    const float* pb = (dir == 0) ? y : x;
    const float* q  = qb + (size_t)b * NPTS * 3;
    const float* p  = pb + (size_t)b * NPTS * 3 + sh * SPTS * 3;

    // Stage shard (coalesced), then fill w = 0.5*|p|^2.
    for (int idx = threadIdx.x; idx < SPTS * 3; idx += BLOCK) {
        int pt = idx / 3;
        int c  = idx - pt * 3;
        ((float*)&pts[pt])[c] = p[idx];
    }
    __syncthreads();
    for (int pt = threadIdx.x; pt < SPTS; pt += BLOCK) {
        float4 v = pts[pt];
        pts[pt].w = 0.5f * fmaf(v.x, v.x, fmaf(v.y, v.y, v.z * v.z));
    }
    __syncthreads();

    // QPT queries per thread, BLOCK-strided (coalesced 12B/lane loads).
    float qx[QPT], qy[QPT], qz[QPT], q2[QPT], best[QPT];
    #pragma unroll
    for (int k = 0; k < QPT; ++k) {
        int qi = threadIdx.x + k * BLOCK;
        qx[k] = q[qi * 3 + 0];
        qy[k] = q[qi * 3 + 1];
        qz[k] = q[qi * 3 + 2];
        q2[k] = fmaf(qx[k], qx[k], fmaf(qy[k], qy[k], qz[k] * qz[k]));
        best[k] = 3.0e38f;
    }

    // Main scan: 2 points/body, 8 queries -> 64 VALU insts per 2 broadcast
    // b128 reads. min3 fusion on the two new scores.
    #pragma unroll 4
    for (int n = 0; n < SPTS; n += 2) {
        float4 pa = pts[n];
        float4 pc = pts[n + 1];
        #pragma unroll
        for (int k = 0; k < QPT; ++k) {
            float sa = fmaf(-qx[k], pa.x, fmaf(-qy[k], pa.y, fmaf(-qz[k], pa.z, pa.w)));
            float sb = fmaf(-qx[k], pc.x, fmaf(-qy[k], pc.y, fmaf(-qz[k], pc.z, pc.w)));
            best[k] = fminf(fminf(best[k], sa), sb);
        }
    }

    if (MODE == 0) {
        #pragma unroll
        for (int k = 0; k < QPT; ++k) {
            int qi = threadIdx.x + k * BLOCK;
            float d = fmaxf(0.0f, fmaf(2.0f, best[k], q2[k]));
            ws[(size_t)sh * NQ + (size_t)(dir * B_SZ + b) * NPTS + qi] = d;
        }
    } else if (MODE == 1) {
        // uint atomicMin is order-preserving for non-negative floats.
        #pragma unroll
        for (int k = 0; k < QPT; ++k) {
            int qi = threadIdx.x + k * BLOCK;
            float d = fmaxf(0.0f, fmaf(2.0f, best[k], q2[k]));
            atomicMin((unsigned int*)ws + (size_t)(dir * B_SZ + b) * NPTS + qi,
                      __float_as_uint(d));
        }
    } else {
        // SSP==1: mins complete, sum directly.
        float s = 0.0f;
        #pragma unroll
        for (int k = 0; k < QPT; ++k)
            s += fmaxf(0.0f, fmaf(2.0f, best[k], q2[k]));
        #pragma unroll
        for (int off = 32; off > 0; off >>= 1) s += __shfl_down(s, off, 64);
        if ((threadIdx.x & 63) == 0) wsum[threadIdx.x >> 6] = s;
        __syncthreads();
        if (threadIdx.x == 0) {
            float tt = 0.f;
            #pragma unroll
            for (int w = 0; w < BLOCK / 64; ++w) tt += wsum[w];
            atomicAdd(out, tt * (1.0f / B_SZ));
        }
    }
}

// MODE 0 reduce: min over SSPLIT shards (pairwise tree), then sum.
// 131072/4/256 = 128 blocks.
__global__ __launch_bounds__(256)
void chamfer_reduce_min_kernel(const float* __restrict__ ws, float* __restrict__ out) {
    __shared__ float wsum[4];
    const int i = blockIdx.x * 256 + threadIdx.x;
    float4 acc[SSPLIT / 2];
    #pragma unroll
    for (int s = 0; s < SSPLIT / 2; ++s) {
        float4 a = ((const float4*)(ws + (size_t)(2 * s) * NQ))[i];
        float4 b = ((const float4*)(ws + (size_t)(2 * s + 1) * NQ))[i];
        acc[s].x = fminf(a.x, b.x); acc[s].y = fminf(a.y, b.y);
        acc[s].z = fminf(a.z, b.z); acc[s].w = fminf(a.w, b.w);
    }
    #pragma unroll
    for (int step = SSPLIT / 4; step > 0; step >>= 1)
        #pragma unroll
        for (int s = 0; s < step; ++s) {
            acc[s].x = fminf(acc[s].x, acc[s + step].x);
            acc[s].y = fminf(acc[s].y, acc[s + step].y);
            acc[s].z = fminf(acc[s].z, acc[s + step].z);
            acc[s].w = fminf(acc[s].w, acc[s + step].w);
        }
    float s = (acc[0].x + acc[0].y) + (acc[0].z + acc[0].w);
    #pragma unroll
    for (int off = 32; off > 0; off >>= 1) s += __shfl_down(s, off, 64);
    if ((threadIdx.x & 63) == 0) wsum[threadIdx.x >> 6] = s;
    __syncthreads();
    if (threadIdx.x == 0) {
        float t = (wsum[0] + wsum[1]) + (wsum[2] + wsum[3]);
        atomicAdd(out, t * (1.0f / B_SZ));
    }
}

// MODE 1 reduce: ws already holds final per-query mins; just sum.
__global__ __launch_bounds__(256)
void chamfer_reduce_sum_kernel(const float* __restrict__ ws, float* __restrict__ out) {
    __shared__ float wsum[4];
    const int i = blockIdx.x * 256 + threadIdx.x;
    float4 v = ((const float4*)ws)[i];
    float s = (v.x + v.y) + (v.z + v.w);
    #pragma unroll
    for (int off = 32; off > 0; off >>= 1) s += __shfl_down(s, off, 64);
    if ((threadIdx.x & 63) == 0) wsum[threadIdx.x >> 6] = s;
    __syncthreads();
    if (threadIdx.x == 0) {
        float t = (wsum[0] + wsum[1]) + (wsum[2] + wsum[3]);
        atomicAdd(out, t * (1.0f / B_SZ));
    }
}

extern "C" void kernel_launch(void* const* d_in, const int* in_sizes, int n_in,
                              void* d_out, int out_size, void* d_ws, size_t ws_size,
                              hipStream_t stream) {
    const float* x = (const float*)d_in[0];
    const float* y = (const float*)d_in[1];
    float* out = (float*)d_out;

    hipMemsetAsync(out, 0, sizeof(float) * out_size, stream);

    const size_t ws_store  = (size_t)SSPLIT * NQ * sizeof(float);  // 8 MB
    const size_t ws_atomic = (size_t)NQ * sizeof(float);           // 512 KB

    if (ws_size >= ws_store) {
        chamfer_min_kernel<SSPLIT, 0>
            <<<2 * B_SZ * SSPLIT, BLOCK, 0, stream>>>(x, y, (float*)d_ws, out);
        chamfer_reduce_min_kernel
            <<<NQ / 4 / 256, 256, 0, stream>>>((const float*)d_ws, out);
    } else if (ws_size >= ws_atomic) {
        hipMemsetAsync(d_ws, 0x7F, ws_atomic, stream);  // 3.39e38 sentinels
        chamfer_min_kernel<SSPLIT, 1>
            <<<2 * B_SZ * SSPLIT, BLOCK, 0, stream>>>(x, y, (float*)d_ws, out);
        chamfer_reduce_sum_kernel
            <<<NQ / 4 / 256, 256, 0, stream>>>((const float*)d_ws, out);
    } else {
        chamfer_min_kernel<1, 2>
            <<<2 * B_SZ, BLOCK, 0, stream>>>(x, y, nullptr, out);
    }
}